// Round 1
// baseline (835.588 us; speedup 1.0000x reference)
//
#include <hip/hip_runtime.h>
#include <math.h>

// Geometry
#define NN   4
#define CI   64
#define DI   16
#define HI   56
#define WI   56
#define CO   128
#define DO_  14
#define HO   54
#define WO   54
#define TAPS 27
#define KINTS 16                      // 64 int8 channels = 16 packed int32
#define M_TOT (NN*DO_*HO*WO)          // 163296 spatial outputs
#define WQ_BYTES (CO*TAPS*CI)         // 221184 (54*4096, aligned)
#define XQ_BYTES (NN*DI*HI*WI*CI)     // 12845056
#define COB 8                         // output channels per block
#define MU_STRIDE 256                 // second m per thread offset

__device__ __forceinline__ int dot4(int a, int b, int c) {
#if __has_builtin(__builtin_amdgcn_sdot4)
    return __builtin_amdgcn_sdot4(a, b, c, false);
#else
    c += (int)(signed char)(a & 0xff)         * (int)(signed char)(b & 0xff);
    c += (int)(signed char)((a >> 8) & 0xff)  * (int)(signed char)((b >> 8) & 0xff);
    c += (int)(signed char)((a >> 16) & 0xff) * (int)(signed char)((b >> 16) & 0xff);
    c += (int)(signed char)(a >> 24)          * (int)(signed char)(b >> 24);
    return c;
#endif
}

// weight [Co][Ci][3][3][3] fp32 -> ws [Co][tap][Ci] int8
__global__ void quant_weight(const float* __restrict__ w, signed char* __restrict__ wq) {
    int i = blockIdx.x * 256 + threadIdx.x;
    if (i >= CO * TAPS * CI) return;
    int c  = i & 63;
    int t  = (i >> 6) % TAPS;
    int co = i / (TAPS * CI);
    float v = w[(co * CI + c) * TAPS + t];
    float q = rintf(v / 0.05f);               // RNE, IEEE div to match np
    q = fminf(fmaxf(q, -128.f), 127.f);
    wq[i] = (signed char)(int)q;
}

// input [N][Ci][D][H][W] fp32 -> ws [N][D][H][W][Ci] int8 (value xq-128)
__global__ void quant_input(const float* __restrict__ x, signed char* __restrict__ xq) {
    int i = blockIdx.x * 256 + threadIdx.x;
    if (i >= XQ_BYTES) return;
    int c = i & 63;
    int s = i >> 6;
    int w_ = s % WI; s /= WI;
    int h_ = s % HI; s /= HI;
    int d_ = s % DI;
    int n_ = s / DI;
    float v = x[(((size_t)(n_ * CI + c) * DI + d_) * HI + h_) * WI + w_];
    float q = rintf(v / 0.05f) + 128.f;
    q = fminf(fmaxf(q, 0.f), 255.f);
    xq[i] = (signed char)((int)q - 128);
}

__launch_bounds__(256)
__global__ void conv_i8(const signed char* __restrict__ xq,
                        const int* __restrict__ wq,
                        const float* __restrict__ bias,
                        float* __restrict__ out) {
    __shared__ int wlds[COB * TAPS * KINTS];   // 13824 B
    const int tid = threadIdx.x;
    const int co_base = blockIdx.y * COB;
    for (int i = tid; i < COB * TAPS * KINTS; i += 256)
        wlds[i] = wq[co_base * TAPS * KINTS + i];
    __syncthreads();

    int m0 = blockIdx.x * (2 * MU_STRIDE) + tid;
    int m1 = m0 + MU_STRIDE;
    const bool v0 = m0 < M_TOT, v1 = m1 < M_TOT;
    int mm0 = v0 ? m0 : 0, mm1 = v1 ? m1 : 0;

    int wo0 = mm0 % WO, t0 = mm0 / WO;
    int ho0 = t0 % HO;  t0 /= HO;
    int dd0 = t0 % DO_; int n0 = t0 / DO_;

    int wo1 = mm1 % WO, t1 = mm1 / WO;
    int ho1 = t1 % HO;  t1 /= HO;
    int dd1 = t1 % DO_; int n1 = t1 / DO_;

    const signed char* p0 = xq + (size_t)(((n0 * DI + dd0) * HI + ho0) * WI + wo0) * CI;
    const signed char* p1 = xq + (size_t)(((n1 * DI + dd1) * HI + ho1) * WI + wo1) * CI;

    int acc0[COB], acc1[COB];
#pragma unroll
    for (int cc = 0; cc < COB; ++cc) { acc0[cc] = 0; acc1[cc] = 0; }

#pragma unroll 1
    for (int kd = 0; kd < 3; ++kd) {
#pragma unroll 1
        for (int kh = 0; kh < 3; ++kh) {
#pragma unroll
            for (int kw = 0; kw < 3; ++kw) {
                const int t = (kd * 3 + kh) * 3 + kw;
                const int off = ((kd * HI + kh) * WI + kw) * CI;
                int4 a0[4], a1[4];
                const int4* q0 = (const int4*)(p0 + off);
                const int4* q1 = (const int4*)(p1 + off);
#pragma unroll
                for (int j = 0; j < 4; ++j) { a0[j] = q0[j]; a1[j] = q1[j]; }
                const int* ai0 = (const int*)a0;
                const int* ai1 = (const int*)a1;
#pragma unroll
                for (int cc = 0; cc < COB; ++cc) {
                    const int* wp = &wlds[(cc * TAPS + t) * KINTS];
#pragma unroll
                    for (int j = 0; j < KINTS; ++j) {
                        const int wv = wp[j];
                        acc0[cc] = dot4(ai0[j], wv, acc0[cc]);
                        acc1[cc] = dot4(ai1[j], wv, acc1[cc]);
                    }
                }
            }
        }
    }

    const float s2 = 0.05f * 0.05f;
#pragma unroll
    for (int cc = 0; cc < COB; ++cc) {
        const int co = co_base + cc;
        const float b = bias[co];
        if (v0) {
            float y = (float)acc0[cc] * s2 + b;
            float q = fminf(fmaxf(rintf(y), 0.f), 255.f);
            out[(((size_t)(n0 * CO + co) * DO_ + dd0) * HO + ho0) * WO + wo0] = q;
        }
        if (v1) {
            float y = (float)acc1[cc] * s2 + b;
            float q = fminf(fmaxf(rintf(y), 0.f), 255.f);
            out[(((size_t)(n1 * CO + co) * DO_ + dd1) * HO + ho1) * WO + wo1] = q;
        }
    }
}

// Fallback: direct fp32 conv with inline quantization (correct, slow).
__global__ void conv_slow(const float* __restrict__ x, const float* __restrict__ w,
                          const float* __restrict__ bias, float* __restrict__ out) {
    size_t o = (size_t)blockIdx.x * 256 + threadIdx.x;
    if (o >= (size_t)M_TOT * CO) return;
    int wo = o % WO; size_t t = o / WO;
    int ho = t % HO; t /= HO;
    int dd = t % DO_; t /= DO_;
    int co = t % CO; int n = t / CO;
    int acc = 0;
    for (int c = 0; c < CI; ++c)
        for (int kd = 0; kd < 3; ++kd)
            for (int kh = 0; kh < 3; ++kh)
                for (int kw = 0; kw < 3; ++kw) {
                    float xv = x[(((size_t)(n * CI + c) * DI + dd + kd) * HI + ho + kh) * WI + wo + kw];
                    float wv = w[((size_t)co * CI + c) * TAPS + (kd * 3 + kh) * 3 + kw];
                    int a  = (int)fminf(fmaxf(rintf(xv / 0.05f) + 128.f, 0.f), 255.f) - 128;
                    int bq = (int)fminf(fmaxf(rintf(wv / 0.05f), -128.f), 127.f);
                    acc += a * bq;
                }
    float y = (float)acc * (0.05f * 0.05f) + bias[co];
    out[o] = fminf(fmaxf(rintf(y), 0.f), 255.f);
}

extern "C" void kernel_launch(void* const* d_in, const int* in_sizes, int n_in,
                              void* d_out, int out_size, void* d_ws, size_t ws_size,
                              hipStream_t stream) {
    const float* x    = (const float*)d_in[0];
    const float* w    = (const float*)d_in[1];
    const float* bias = (const float*)d_in[2];
    float* out = (float*)d_out;

    const size_t need = (size_t)WQ_BYTES + (size_t)XQ_BYTES;
    if (ws_size >= need) {
        signed char* wq8 = (signed char*)d_ws;
        signed char* xq8 = (signed char*)d_ws + WQ_BYTES;
        hipLaunchKernelGGL(quant_weight, dim3((CO * TAPS * CI + 255) / 256), dim3(256), 0, stream, w, wq8);
        hipLaunchKernelGGL(quant_input, dim3((XQ_BYTES + 255) / 256), dim3(256), 0, stream, x, xq8);
        const int gx = (M_TOT + 2 * MU_STRIDE - 1) / (2 * MU_STRIDE);  // 319
        hipLaunchKernelGGL(conv_i8, dim3(gx, CO / COB, 1), dim3(256), 0, stream,
                           xq8, (const int*)wq8, bias, out);
    } else {
        const size_t tot = (size_t)M_TOT * CO;
        hipLaunchKernelGGL(conv_slow, dim3((unsigned)((tot + 255) / 256)), dim3(256), 0, stream,
                           x, w, bias, out);
    }
}

// Round 2
// 252.340 us; speedup vs baseline: 3.3114x; 3.3114x over previous
//
#include <hip/hip_runtime.h>
#include <math.h>

// Geometry
#define NN   4
#define CI   64
#define DI   16
#define HI   56
#define WI   56
#define CO   128
#define DO_  14
#define HO   54
#define WO   54
#define TAPS 27
#define SP   (DO_*HO*WO)              // 40824 output spatial per n
#define M_TOT (NN*SP)                 // 163296 spatial outputs
#define WQ_BYTES (CO*TAPS*CI)         // 221184
#define XQ_BYTES ((size_t)NN*DI*HI*WI*CI)  // 12845056

typedef int i32x4 __attribute__((ext_vector_type(4)));

// weight [Co][Ci][3][3][3] fp32 -> ws [Co][tap][Ci] int8
__global__ void quant_weight(const float* __restrict__ w, signed char* __restrict__ wq) {
    int i = blockIdx.x * 256 + threadIdx.x;
    if (i >= CO * TAPS * CI) return;
    int c  = i & 63;
    int t  = (i >> 6) % TAPS;
    int co = i / (TAPS * CI);
    float v = w[(co * CI + c) * TAPS + t];
    float q = rintf(v / 0.05f);               // RNE, IEEE div to match np
    q = fminf(fmaxf(q, -128.f), 127.f);
    wq[i] = (signed char)(int)q;
}

// input [N][Ci][D][H][W] fp32 -> ws [N][D][H][W][Ci] int8 (value xq-128)
__global__ void quant_input(const float* __restrict__ x, signed char* __restrict__ xq) {
    size_t i = (size_t)blockIdx.x * 256 + threadIdx.x;
    if (i >= XQ_BYTES) return;
    int c = (int)(i & 63);
    size_t s = i >> 6;
    int w_ = (int)(s % WI); s /= WI;
    int h_ = (int)(s % HI); s /= HI;
    int d_ = (int)(s % DI);
    int n_ = (int)(s / DI);
    float v = x[(((size_t)(n_ * CI + c) * DI + d_) * HI + h_) * WI + w_];
    float q = rintf(v / 0.05f) + 128.f;
    q = fminf(fmaxf(q, 0.f), 255.f);
    xq[i] = (signed char)((int)q - 128);
}

// Implicit GEMM: M=163296 (n,do,ho,wo), N=128 (co), K=1728 (27 taps x 64 ci).
// One tap == one K=64 step of mfma_i32_16x16x64_i8.
// Per wave: 32 m-rows (2 A frags) x 128 co (8 B tiles), 27 taps.
__launch_bounds__(256)
__global__ void conv_mfma(const signed char* __restrict__ xq,
                          const signed char* __restrict__ wq,
                          const float* __restrict__ bias,
                          float* __restrict__ out) {
    const int lane = threadIdx.x & 63;
    const int wave = threadIdx.x >> 6;
    const int m_base = blockIdx.x * 128 + wave * 32;
    if (m_base >= M_TOT) return;
    const int l16 = lane & 15;
    const int kg  = lane >> 4;       // 0..3, k-group: ci = kg*16 + j

    // A row base offsets (two 16-row fragments)
    int in_off0, in_off1;
    {
        int m = m_base + l16;
        int n = m / SP;
        int rem = m - n * SP;
        int d = rem / (HO * WO);
        int r2 = rem - d * (HO * WO);
        int h = r2 / WO;
        int w = r2 - h * WO;
        in_off0 = (((n * DI + d) * HI + h) * WI + w) * CI;
    }
    {
        int m = m_base + 16 + l16;
        int n = m / SP;
        int rem = m - n * SP;
        int d = rem / (HO * WO);
        int r2 = rem - d * (HO * WO);
        int h = r2 / WO;
        int w = r2 - h * WO;
        in_off1 = (((n * DI + d) * HI + h) * WI + w) * CI;
    }
    const signed char* a0p = xq + in_off0 + kg * 16;
    const signed char* a1p = xq + in_off1 + kg * 16;

    // B base: lane's column l16, k-group kg
    const signed char* bp0 = wq + (size_t)l16 * (TAPS * CI) + kg * 16;

    i32x4 acc[2][8];
#pragma unroll
    for (int f = 0; f < 2; ++f)
#pragma unroll
        for (int c = 0; c < 8; ++c)
            acc[f][c] = (i32x4){0, 0, 0, 0};

#pragma unroll
    for (int kd = 0; kd < 3; ++kd) {
#pragma unroll
        for (int kh = 0; kh < 3; ++kh) {
            const signed char* ar0 = a0p + ((kd * HI + kh) * WI) * CI;
            const signed char* ar1 = a1p + ((kd * HI + kh) * WI) * CI;
#pragma unroll
            for (int kw = 0; kw < 3; ++kw) {
                const int t = (kd * 3 + kh) * 3 + kw;
                i32x4 a0 = *(const i32x4*)(ar0 + kw * CI);
                i32x4 a1 = *(const i32x4*)(ar1 + kw * CI);
#pragma unroll
                for (int c = 0; c < 8; ++c) {
                    i32x4 b = *(const i32x4*)(bp0 + (size_t)c * 16 * (TAPS * CI) + t * CI);
                    acc[0][c] = __builtin_amdgcn_mfma_i32_16x16x64_i8(a0, b, acc[0][c], 0, 0, 0);
                    acc[1][c] = __builtin_amdgcn_mfma_i32_16x16x64_i8(a1, b, acc[1][c], 0, 0, 0);
                }
            }
        }
    }

    // Epilogue: requant + store. out[n][co][d][h][w]; idx = m + n*SP*(CO-1) + co*SP
    const float s2 = 0.05f * 0.05f;
    float bco[8];
#pragma unroll
    for (int c = 0; c < 8; ++c) bco[c] = bias[c * 16 + l16];

#pragma unroll
    for (int f = 0; f < 2; ++f) {
#pragma unroll
        for (int r = 0; r < 4; ++r) {
            int m = m_base + f * 16 + kg * 4 + r;
            int n = m / SP;
            size_t base = (size_t)m + (size_t)n * (SP * (CO - 1));
#pragma unroll
            for (int c = 0; c < 8; ++c) {
                float y = (float)acc[f][c][r] * s2 + bco[c];
                float q = fminf(fmaxf(rintf(y), 0.f), 255.f);
                out[base + (size_t)(c * 16 + l16) * SP] = q;
            }
        }
    }
}

// Fallback: direct fp32 conv with inline quantization (correct, slow).
__global__ void conv_slow(const float* __restrict__ x, const float* __restrict__ w,
                          const float* __restrict__ bias, float* __restrict__ out) {
    size_t o = (size_t)blockIdx.x * 256 + threadIdx.x;
    if (o >= (size_t)M_TOT * CO) return;
    int wo = o % WO; size_t t = o / WO;
    int ho = t % HO; t /= HO;
    int dd = t % DO_; t /= DO_;
    int co = t % CO; int n = t / CO;
    int acc = 0;
    for (int c = 0; c < CI; ++c)
        for (int kd = 0; kd < 3; ++kd)
            for (int kh = 0; kh < 3; ++kh)
                for (int kw = 0; kw < 3; ++kw) {
                    float xv = x[(((size_t)(n * CI + c) * DI + dd + kd) * HI + ho + kh) * WI + wo + kw];
                    float wv = w[((size_t)co * CI + c) * TAPS + (kd * 3 + kh) * 3 + kw];
                    int a  = (int)fminf(fmaxf(rintf(xv / 0.05f) + 128.f, 0.f), 255.f) - 128;
                    int bq = (int)fminf(fmaxf(rintf(wv / 0.05f), -128.f), 127.f);
                    acc += a * bq;
                }
    float y = (float)acc * (0.05f * 0.05f) + bias[co];
    out[o] = fminf(fmaxf(rintf(y), 0.f), 255.f);
}

extern "C" void kernel_launch(void* const* d_in, const int* in_sizes, int n_in,
                              void* d_out, int out_size, void* d_ws, size_t ws_size,
                              hipStream_t stream) {
    const float* x    = (const float*)d_in[0];
    const float* w    = (const float*)d_in[1];
    const float* bias = (const float*)d_in[2];
    float* out = (float*)d_out;

    const size_t need = (size_t)WQ_BYTES + XQ_BYTES;
    if (ws_size >= need) {
        signed char* wq8 = (signed char*)d_ws;
        signed char* xq8 = (signed char*)d_ws + WQ_BYTES;
        hipLaunchKernelGGL(quant_weight, dim3((CO * TAPS * CI + 255) / 256), dim3(256), 0, stream, w, wq8);
        hipLaunchKernelGGL(quant_input, dim3((unsigned)((XQ_BYTES + 255) / 256)), dim3(256), 0, stream, x, xq8);
        hipLaunchKernelGGL(conv_mfma, dim3((M_TOT + 127) / 128), dim3(256), 0, stream,
                           xq8, wq8, bias, out);
    } else {
        const size_t tot = (size_t)M_TOT * CO;
        hipLaunchKernelGGL(conv_slow, dim3((unsigned)((tot + 255) / 256)), dim3(256), 0, stream,
                           x, w, bias, out);
    }
}

// Round 3
// 84.589 us; speedup vs baseline: 9.8783x; 2.9831x over previous
//
#include <hip/hip_runtime.h>
#include <math.h>

// Geometry
#define NN   4
#define CI   64
#define DI   16
#define HI   56
#define WI   56
#define CO   128
#define DO_  14
#define HO   54
#define WO   54
#define TAPS 27
#define SPI  (DI*HI*WI)               // 50176 input spatial per n
#define SP   (DO_*HO*WO)              // 40824 output spatial per n
#define M_TOT (NN*SP)                 // 163296
#define WQ_BYTES (CO*TAPS*CI)         // 221184
#define XQ_BYTES ((size_t)NN*SPI*CI)  // 12845056
#define SLICE_B 24576                 // 3 taps * 4 kg * 128 co * 16B

typedef int i32x4 __attribute__((ext_vector_type(4)));

// weight [Co][Ci][3][3][3] fp32 -> wq2 [tap][kg][co][ci16] int8
__global__ void quant_weight(const float* __restrict__ w, signed char* __restrict__ wq) {
    int i = blockIdx.x * 256 + threadIdx.x;
    if (i >= CO * TAPS * CI) return;
    int c  = i & 63;
    int t  = (i >> 6) % TAPS;
    int co = i / (TAPS * CI);
    float v = w[(co * CI + c) * TAPS + t];
    float q = rintf(v / 0.05f);               // RNE, IEEE div to match np
    q = fminf(fmaxf(q, -128.f), 127.f);
    wq[((t * 4 + (c >> 4)) * 128 + co) * 16 + (c & 15)] = (signed char)(int)q;
}

// input [N][Ci][D][H][W] fp32 -> xq [N][D][H][W][Ci] int8 (value xq-128)
// one thread per spatial point; per-c iteration is wave-coalesced (256B).
__launch_bounds__(256)
__global__ void quant_input(const float* __restrict__ x, signed char* __restrict__ xq) {
    int sp = blockIdx.x * 256 + threadIdx.x;      // 0..200703 (784*256 exact)
    int n  = sp / SPI;
    int spl = sp - n * SPI;
    const float* src = x + (size_t)n * CI * SPI + spl;
    union { signed char b[64]; i32x4 v[4]; } pk;
#pragma unroll
    for (int c = 0; c < CI; ++c) {
        float v = src[(size_t)c * SPI];
        float q = rintf(v / 0.05f) + 128.f;
        q = fminf(fmaxf(q, 0.f), 255.f);
        pk.b[c] = (signed char)((int)q - 128);
    }
    i32x4* dst = (i32x4*)(xq + (size_t)sp * 64);
#pragma unroll
    for (int j = 0; j < 4; ++j) dst[j] = pk.v[j];
}

// Implicit GEMM, operands swapped vs R2: A=weights (rows=co), B=input (cols=m).
// C: col=lane&15 = m (consecutive!), row=(lane>>4)*4+r = co_local -> coalesced stores.
// Weights double-buffered in LDS per (kd,kh) slice; X prefetched one slice ahead.
__launch_bounds__(256)
__global__ void conv_mfma(const signed char* __restrict__ xq,
                          const signed char* __restrict__ wq,
                          const float* __restrict__ bias,
                          float* __restrict__ out) {
    __shared__ signed char lds[2][SLICE_B];
    const int tid  = threadIdx.x;
    const int lane = tid & 63;
    const int wave = tid >> 6;
    const int l16  = lane & 15;
    const int kg   = lane >> 4;

    int m_base = blockIdx.x * 128 + wave * 32;
    const bool valid = m_base < M_TOT;
    if (!valid) m_base = 0;                 // stay alive for staging/barriers

    // X row base per m-frag (output coords -> input row start)
    const signed char* xrow[2];
#pragma unroll
    for (int f = 0; f < 2; ++f) {
        int m = m_base + f * 16 + l16;
        int n = m / SP;
        int rem = m - n * SP;
        int d = rem / (HO * WO);
        int r2 = rem - d * (HO * WO);
        int h = r2 / WO;
        int w = r2 - h * WO;
        xrow[f] = xq + (size_t)(((n * DI + d) * HI + h) * WI + w) * CI + kg * 16;
    }

    // --- staging helper: 24576B linear, 6 x 16B per thread ---
    auto STAGE = [&](const signed char* src, signed char* dst) {
#pragma unroll
        for (int i = 0; i < 6; ++i) {
            __builtin_amdgcn_global_load_lds(
                (const __attribute__((address_space(1))) void*)(src + i * 4096 + tid * 16),
                (__attribute__((address_space(3))) void*)(dst + i * 4096 + tid * 16),
                16, 0, 0);
        }
    };
    // --- X fragment loads for slice s ---
    auto LOADX = [&](int s, i32x4 xf[2][3]) {
        int kd = s / 3, kh = s % 3;
        int xoff = ((kd * HI + kh) * WI) * CI;
#pragma unroll
        for (int f = 0; f < 2; ++f)
#pragma unroll
            for (int kw = 0; kw < 3; ++kw)
                xf[f][kw] = *(const i32x4*)(xrow[f] + xoff + kw * CI);
    };

    i32x4 acc[2][8];
#pragma unroll
    for (int f = 0; f < 2; ++f)
#pragma unroll
        for (int c = 0; c < 8; ++c)
            acc[f][c] = (i32x4){0, 0, 0, 0};

    i32x4 xa[2][3], xb[2][3];
    STAGE(wq, lds[0]);
    LOADX(0, xa);

#pragma unroll
    for (int s = 0; s < 9; ++s) {
        __syncthreads();                         // stage(s) + prefetch-X landed
        if (s < 8) {
            STAGE(wq + (s + 1) * SLICE_B, lds[(s + 1) & 1]);
            if (s & 1) LOADX(s + 1, xa); else LOADX(s + 1, xb);
        }
        const signed char* buf = lds[s & 1];
        i32x4 (*xf)[3] = (s & 1) ? xb : xa;
#pragma unroll
        for (int kw = 0; kw < 3; ++kw) {
            i32x4 wf[8];
#pragma unroll
            for (int c = 0; c < 8; ++c)
                wf[c] = *(const i32x4*)(buf + kw * 8192 + kg * 2048 + (c * 16 + l16) * 16);
#pragma unroll
            for (int c = 0; c < 8; ++c) {
                acc[0][c] = __builtin_amdgcn_mfma_i32_16x16x64_i8(wf[c], xf[0][kw], acc[0][c], 0, 0, 0);
                acc[1][c] = __builtin_amdgcn_mfma_i32_16x16x64_i8(wf[c], xf[1][kw], acc[1][c], 0, 0, 0);
            }
        }
    }

    if (!valid) return;
    const float s2 = 0.05f * 0.05f;
#pragma unroll
    for (int f = 0; f < 2; ++f) {
        int m = m_base + f * 16 + l16;
        int n = m / SP;
        int sp = m - n * SP;
        float* obase = out + (size_t)n * CO * SP + sp;
#pragma unroll
        for (int c = 0; c < 8; ++c) {
#pragma unroll
            for (int r = 0; r < 4; ++r) {
                int co = c * 16 + kg * 4 + r;
                float y = (float)acc[f][c][r] * s2 + bias[co];
                float q = fminf(fmaxf(rintf(y), 0.f), 255.f);
                obase[(size_t)co * SP] = q;
            }
        }
    }
}

// Fallback: direct fp32 conv with inline quantization (correct, slow).
__global__ void conv_slow(const float* __restrict__ x, const float* __restrict__ w,
                          const float* __restrict__ bias, float* __restrict__ out) {
    size_t o = (size_t)blockIdx.x * 256 + threadIdx.x;
    if (o >= (size_t)M_TOT * CO) return;
    int wo = o % WO; size_t t = o / WO;
    int ho = t % HO; t /= HO;
    int dd = t % DO_; t /= DO_;
    int co = t % CO; int n = t / CO;
    int acc = 0;
    for (int c = 0; c < CI; ++c)
        for (int kd = 0; kd < 3; ++kd)
            for (int kh = 0; kh < 3; ++kh)
                for (int kw = 0; kw < 3; ++kw) {
                    float xv = x[(((size_t)(n * CI + c) * DI + dd + kd) * HI + ho + kh) * WI + wo + kw];
                    float wv = w[((size_t)co * CI + c) * TAPS + (kd * 3 + kh) * 3 + kw];
                    int a  = (int)fminf(fmaxf(rintf(xv / 0.05f) + 128.f, 0.f), 255.f) - 128;
                    int bq = (int)fminf(fmaxf(rintf(wv / 0.05f), -128.f), 127.f);
                    acc += a * bq;
                }
    float y = (float)acc * (0.05f * 0.05f) + bias[co];
    out[o] = fminf(fmaxf(rintf(y), 0.f), 255.f);
}

extern "C" void kernel_launch(void* const* d_in, const int* in_sizes, int n_in,
                              void* d_out, int out_size, void* d_ws, size_t ws_size,
                              hipStream_t stream) {
    const float* x    = (const float*)d_in[0];
    const float* w    = (const float*)d_in[1];
    const float* bias = (const float*)d_in[2];
    float* out = (float*)d_out;

    const size_t need = (size_t)WQ_BYTES + XQ_BYTES;
    if (ws_size >= need) {
        signed char* wq8 = (signed char*)d_ws;
        signed char* xq8 = (signed char*)d_ws + WQ_BYTES;
        hipLaunchKernelGGL(quant_weight, dim3((CO * TAPS * CI + 255) / 256), dim3(256), 0, stream, w, wq8);
        hipLaunchKernelGGL(quant_input, dim3((NN * SPI) / 256), dim3(256), 0, stream, x, xq8);
        hipLaunchKernelGGL(conv_mfma, dim3((M_TOT + 127) / 128), dim3(256), 0, stream,
                           xq8, wq8, bias, out);
    } else {
        const size_t tot = (size_t)M_TOT * CO;
        hipLaunchKernelGGL(conv_slow, dim3((unsigned)((tot + 255) / 256)), dim3(256), 0, stream,
                           x, w, bias, out);
    }
}